// Round 7
// baseline (384.525 us; speedup 1.0000x reference)
//
#include <hip/hip_runtime.h>
#include <math.h>

#define NB_B 512
#define NE 100000
#define DD 200
#define CC 32
#define FCIN 10368   // 32*18*18
#define HW 324       // 18*18
#define BNEPS 1e-5f
#define KP 224       // scores K padded to multiple of 32 for MFMA

#define FCW_BLKS 1013
#define GATH_OFF FCW_BLKS   // gather blocks start here

typedef __attribute__((ext_vector_type(8))) short short8;   // 8 bf16 = 4 VGPRs
typedef __attribute__((ext_vector_type(4))) float floatx4;  // MFMA acc

// dacc (double) slots:
// 0: bn0 sum, 1: bn0 sumsq (also l2 for h_e+r_e)
// 2..33: bn1 per-channel sum, 34..65: bn1 per-channel sumsq
// 67: fc_w sumsq, 68: softplus sum (incl. pad constant), 69: scores sum, 70: pos-scores sum

static __device__ __forceinline__ float blk_reduce(float v, volatile float* sbuf) {
  for (int o = 32; o > 0; o >>= 1) v += __shfl_down(v, o, 64);
  int lane = threadIdx.x & 63, wid = threadIdx.x >> 6;
  if (lane == 0) sbuf[wid] = v;
  __syncthreads();
  float r = 0.f;
  int nw = (blockDim.x + 63) >> 6;
  if ((int)threadIdx.x < nw) r = sbuf[threadIdx.x];
  if (threadIdx.x < 64) {
    for (int o = 32; o > 0; o >>= 1) r += __shfl_down(r, o, 64);
  }
  __syncthreads();
  return r;  // valid on thread 0
}

static __device__ __forceinline__ unsigned short f32_to_bf16(float f) {
  unsigned int u = __float_as_uint(f);
  u += 0x7fffu + ((u >> 16) & 1u);  // round-to-nearest-even
  return (unsigned short)(u >> 16);
}
static __device__ __forceinline__ float bf16_to_f32(unsigned short b) {
  return __uint_as_float(((unsigned int)b) << 16);
}

// K1: fused prep. Blocks [0,FCW_BLKS): fc_w -> bf16 + sumsq.
// Blocks [GATH_OFF, +512): gather h/r -> x0, bn0 stats.
// (entity f32->bf16 conversion fused into k_scores5 staging)
__global__ __launch_bounds__(256) void k_cvt(const float* __restrict__ fcw,
                                             unsigned short* __restrict__ fcwb,
                                             const float* __restrict__ ent,
                                             const float* __restrict__ rel,
                                             const int* __restrict__ h,
                                             const int* __restrict__ r,
                                             float* __restrict__ x0,
                                             double* dacc) {
  if (blockIdx.x < FCW_BLKS) {
    int g = blockIdx.x * 256 + threadIdx.x;   // x8 elems; 2,073,600 total
    float sq = 0.f;
    if (g < 259200) {
      const float4* s = (const float4*)(fcw + (long)g * 8);
      float4 u = s[0], v = s[1];
      sq = u.x*u.x + u.y*u.y + u.z*u.z + u.w*u.w
         + v.x*v.x + v.y*v.y + v.z*v.z + v.w*v.w;
      ushort4 o0, o1;
      o0.x = f32_to_bf16(u.x); o0.y = f32_to_bf16(u.y);
      o0.z = f32_to_bf16(u.z); o0.w = f32_to_bf16(u.w);
      o1.x = f32_to_bf16(v.x); o1.y = f32_to_bf16(v.y);
      o1.z = f32_to_bf16(v.z); o1.w = f32_to_bf16(v.w);
      ushort4* d = (ushort4*)(fcwb + (long)g * 8);
      d[0] = o0; d[1] = o1;
    }
    __shared__ float sbuf[8];
    float tq = blk_reduce(sq, sbuf);
    if (threadIdx.x == 0) atomicAdd(&dacc[67], (double)tq);
  } else {
    int b = blockIdx.x - GATH_OFF;
    int hi = h[b], ri = r[b];
    float s = 0.f, sq = 0.f;
    for (int i = threadIdx.x; i < 400; i += 256) {
      float v = (i < 200) ? ent[(long)hi * DD + i] : rel[(long)ri * DD + (i - 200)];
      x0[b * 400 + i] = v;
      s += v; sq += v * v;
    }
    __shared__ float sbuf[8];
    float ts = blk_reduce(s, sbuf);
    float tq = blk_reduce(sq, sbuf);
    if (threadIdx.x == 0) {
      atomicAdd(&dacc[0], (double)ts);
      atomicAdd(&dacc[1], (double)tq);
    }
  }
}

// K2: bn0 + conv3x3 + conv_b -> yb bf16 [512 x 10368] (pre-bn1); bn1 stats (f32)
__global__ __launch_bounds__(256) void k_conv(const float* __restrict__ x0,
                       const float* __restrict__ convw, const float* __restrict__ convb,
                       const float* __restrict__ g0, const float* __restrict__ b0,
                       unsigned short* __restrict__ yb, double* dacc) {
  __shared__ float xs[400], wsm[288], cbs[32], ssum[32], ssq[32];
  __shared__ float a0s, s0s;
  int b = blockIdx.x, t = threadIdx.x;
  for (int i = t; i < 400; i += 256) xs[i] = x0[b * 400 + i];
  for (int i = t; i < 288; i += 256) wsm[i] = convw[i];
  if (t < 32) cbs[t] = convb[t];
  if (t == 0) {
    double m = dacc[0] / 204800.0;
    double v = dacc[1] / 204800.0 - m * m;
    float a = g0[0] * rsqrtf((float)v + BNEPS);
    a0s = a; s0s = b0[0] - (float)m * a;
  }
  __syncthreads();
  float a0 = a0s, s0 = s0s;
  for (int i = t; i < 400; i += 256) xs[i] = a0 * xs[i] + s0;
  __syncthreads();
  int c = t >> 3, sub = t & 7;
  const float* w = &wsm[c * 9];
  float cb = cbs[c];
  float s = 0.f, sq = 0.f;
  for (int e = sub; e < HW; e += 8) {
    int oh = e / 18, ow = e - oh * 18;
    const float* xp = &xs[oh * 20 + ow];
    float acc = cb
       + xp[0] * w[0] + xp[1] * w[1] + xp[2] * w[2]
       + xp[20] * w[3] + xp[21] * w[4] + xp[22] * w[5]
       + xp[40] * w[6] + xp[41] * w[7] + xp[42] * w[8];
    yb[(long)b * FCIN + c * HW + e] = f32_to_bf16(acc);
    s += acc; sq += acc * acc;
  }
  s += __shfl_xor(s, 1, 64); sq += __shfl_xor(sq, 1, 64);
  s += __shfl_xor(s, 2, 64); sq += __shfl_xor(sq, 2, 64);
  s += __shfl_xor(s, 4, 64); sq += __shfl_xor(sq, 4, 64);
  if (sub == 0) { ssum[c] = s; ssq[c] = sq; }
  __syncthreads();
  if (t < 32) {
    atomicAdd(&dacc[2 + t], (double)ssum[t]);
    atomicAdd(&dacc[34 + t], (double)ssq[t]);
  }
}

// K3: in-place bn1 + relu on yb (bf16); a1/sh1 computed per-block from dacc
__global__ __launch_bounds__(256) void k_prep(unsigned short* __restrict__ yb,
                                              const float* __restrict__ g1,
                                              const float* __restrict__ b1,
                                              const double* __restrict__ dacc) {
  __shared__ float a1s[32], sh1s[32];
  int t = threadIdx.x;
  if (t < 32) {
    double cnt = 512.0 * 324.0;
    double m = dacc[2 + t] / cnt, v = dacc[34 + t] / cnt - m * m;
    float a = g1[t] * rsqrtf((float)v + BNEPS);
    a1s[t] = a; sh1s[t] = b1[t] - (float)m * a;
  }
  __syncthreads();
  int g = blockIdx.x * 256 + t;          // 0..663551 (x8 elems)
  int row = g / 1296;
  int c8 = (g - row * 1296) * 8;
  unsigned short* p = yb + (long)row * FCIN + c8;
  ushort4 v0 = ((ushort4*)p)[0], v1 = ((ushort4*)p)[1];
  unsigned short e[8] = {v0.x, v0.y, v0.z, v0.w, v1.x, v1.y, v1.z, v1.w};
#pragma unroll
  for (int j = 0; j < 8; j++) {
    int c = (c8 + j) / HW;
    float f = a1s[c] * bf16_to_f32(e[j]) + sh1s[c];
    e[j] = f32_to_bf16(fmaxf(f, 0.f));
  }
  v0.x = e[0]; v0.y = e[1]; v0.z = e[2]; v0.w = e[3];
  v1.x = e[4]; v1.y = e[5]; v1.z = e[6]; v1.w = e[7];
  ((ushort4*)p)[0] = v0; ((ushort4*)p)[1] = v1;
}

// K4: FC GEMM via bf16 MFMA. 384 single-wave blocks = 12 kslices x (8 mt x 4 nt).
__global__ __launch_bounds__(64) void k_fc3(const unsigned short* __restrict__ yb,
                                            const unsigned short* __restrict__ fcwb,
                                            float* __restrict__ Cp) {
  int wid = blockIdx.x;             // 384 = 12 ks * 32 tiles
  int ks = wid >> 5, rem = wid & 31;
  int mt = rem >> 2, nt = rem & 3;
  int m0 = mt * 64, n0 = nt * 64;
  int lane = threadIdx.x;
  int quad = lane >> 4, lr = lane & 15;
  long kbeg = (long)ks * 864;       // 27 chunks of 32

  const unsigned short* arow[4];
  const unsigned short* brow[4];
#pragma unroll
  for (int mi = 0; mi < 4; mi++)
    arow[mi] = yb + (long)(m0 + mi * 16 + lr) * FCIN + kbeg + quad * 8;
#pragma unroll
  for (int ni = 0; ni < 4; ni++) {
    int d = n0 + ni * 16 + lr;
    if (d > DD - 1) d = DD - 1;
    brow[ni] = fcwb + (long)d * FCIN + kbeg + quad * 8;
  }

  floatx4 acc[4][4];
#pragma unroll
  for (int i = 0; i < 4; i++)
#pragma unroll
    for (int j = 0; j < 4; j++) acc[i][j] = (floatx4){0.f, 0.f, 0.f, 0.f};

  short8 sA[3][4], sB[3][4];
#pragma unroll
  for (int c = 0; c < 3; c++) {
#pragma unroll
    for (int mi = 0; mi < 4; mi++) sA[c][mi] = *(const short8*)(arow[mi] + c * 32);
#pragma unroll
    for (int ni = 0; ni < 4; ni++) sB[c][ni] = *(const short8*)(brow[ni] + c * 32);
  }
  for (int c3 = 0; c3 < 9; c3++) {
    int cc = c3 * 3;
#pragma unroll
    for (int j = 0; j < 3; j++) {
#pragma unroll
      for (int ni = 0; ni < 4; ni++)
#pragma unroll
        for (int mi = 0; mi < 4; mi++)
          acc[mi][ni] = __builtin_amdgcn_mfma_f32_16x16x32_bf16(sA[j][mi], sB[j][ni], acc[mi][ni], 0, 0, 0);
      int nxt = cc + j + 3;
      if (nxt < 27) {
#pragma unroll
        for (int mi = 0; mi < 4; mi++) sA[j][mi] = *(const short8*)(arow[mi] + nxt * 32);
#pragma unroll
        for (int ni = 0; ni < 4; ni++) sB[j][ni] = *(const short8*)(brow[ni] + nxt * 32);
      }
    }
  }

  float* out = Cp + (long)ks * (NB_B * DD);
#pragma unroll
  for (int ni = 0; ni < 4; ni++) {
    int d = n0 + ni * 16 + lr;
    if (d < DD) {
#pragma unroll
      for (int mi = 0; mi < 4; mi++) {
        int mbase = m0 + mi * 16 + quad * 4;
#pragma unroll
        for (int rg = 0; rg < 4; rg++)
          out[(mbase + rg) * DD + d] = acc[mi][ni][rg];
      }
    }
  }
}

// K4b: reduce 12 partials -> Cfc. 102400 floats = 25600 float4.
__global__ __launch_bounds__(256) void k_fcred(const float* __restrict__ Cp,
                                               float* __restrict__ Cfc) {
  int g = blockIdx.x * 256 + threadIdx.x;   // 0..25599
  float4 s = ((const float4*)Cp)[g];
#pragma unroll
  for (int p = 1; p < 12; p++) {
    float4 v = ((const float4*)(Cp + (long)p * (NB_B * DD)))[g];
    s.x += v.x; s.y += v.y; s.z += v.z; s.w += v.w;
  }
  ((float4*)Cfc)[g] = s;
}

// K5: bn2 stats per feature -> a2/b2c
__global__ void k_bn2stats(const float* __restrict__ Cfc, const float* __restrict__ fcb,
                           const float* __restrict__ g2, const float* __restrict__ b2,
                           float* __restrict__ a2, float* __restrict__ b2c) {
  int d = blockIdx.x, lane = threadIdx.x;  // 64 threads
  float s = 0.f, sq = 0.f;
  for (int b = lane; b < NB_B; b += 64) {
    float v = Cfc[b * DD + d] + fcb[d];
    s += v; sq += v * v;
  }
  for (int o = 32; o > 0; o >>= 1) { s += __shfl_down(s, o, 64); sq += __shfl_down(sq, o, 64); }
  if (lane == 0) {
    float m = s / 512.f, v = sq / 512.f - m * m;
    float a = g2[d] * rsqrtf(v + BNEPS);
    a2[d] = a; b2c[d] = b2[d] - m * a;
  }
}

// K6: x_final row: leaky_relu(bn2(fc)) -> xf f32 + xfb bf16(padded); fused pos-score
__global__ __launch_bounds__(256) void k_xfinal(const float* __restrict__ Cfc,
                         const float* __restrict__ fcb,
                         const float* __restrict__ a2, const float* __restrict__ b2c,
                         const float* __restrict__ ent, const float* __restrict__ bias,
                         const int* __restrict__ pos,
                         float* __restrict__ xf, unsigned short* __restrict__ xfb,
                         double* dacc) {
  __shared__ float xs[224];
  __shared__ float sbuf[8];
  int b = blockIdx.x, t = threadIdx.x;
  if (t < KP) {
    float xv = 0.f;
    if (t < DD) {
      float v = Cfc[b * DD + t] + fcb[t];
      xv = a2[t] * v + b2c[t];
      xv = xv >= 0.f ? xv : 0.01f * xv;
      xf[b * DD + t] = xv;
    }
    xfb[b * KP + t] = f32_to_bf16(xv);
    xs[t] = xv;
  }
  __syncthreads();
  int e = pos[b];
  float s = (t < DD) ? xs[t] * ent[(long)e * DD + t] : 0.f;
  float ts = blk_reduce(s, sbuf);
  if (t == 0) atomicAdd(&dacc[70], (double)(ts + bias[e]));
}

// ---------------------------------------------------------------------------
// K7: scores GEMM + fused softplus, LDS-staged entity tiles with fused
// f32->bf16 conversion.
//
// Round-4 post-mortem fix: the previous version spilled ~100 VGPRs/thread
// (WRITE_SIZE 134 MB of scratch = 448B/thr x 512thr x 521blk). Two changes:
//   1. amdgpu_waves_per_eu(2,2): pin 2 waves/EU -> 256-VGPR budget
//      (launch_bounds(512,2) made the allocator cap at 128 and spill).
//   2. sc_compute restructured ni-outer: acc[4] (16 VGPRs) live instead of
//      acc[4][4] (64), softplus epilogue per-ni. Same MFMA / LDS-read count;
//      4 independent mi-chains preserve MFMA ILP.
// Live set now ~af(112) + rg(28) + acc(16) + misc ~= 185 < 256 -> no spill.
// ---------------------------------------------------------------------------
static __device__ __forceinline__ void sc_stage_issue(
    const float* __restrict__ ent, int e0, int t, float4 (&rg)[7]) {
#pragma unroll
  for (int i = 0; i < 7; i++) {
    int u = t + i * 512;           // 0..3583
    int rr = u / 56, j = u - rr * 56;
    int e = e0 + rr;
    float4 v; v.x = 0.f; v.y = 0.f; v.z = 0.f; v.w = 0.f;
    if (j < 50 && e < NE) v = *(const float4*)(ent + (long)e * DD + j * 4);
    rg[i] = v;
  }
}

static __device__ __forceinline__ void sc_stage_commit(
    unsigned short* __restrict__ buf, int t, const float4 (&rg)[7]) {
  char* base = (char*)buf;
#pragma unroll
  for (int i = 0; i < 7; i++) {
    int u = t + i * 512;
    int rr = u / 56, j = u - rr * 56;
    int c = j >> 1, h = j & 1;
    int rrx = rr ^ (c & 7);
    ushort4 o;
    o.x = f32_to_bf16(rg[i].x); o.y = f32_to_bf16(rg[i].y);
    o.z = f32_to_bf16(rg[i].z); o.w = f32_to_bf16(rg[i].w);
    *(ushort4*)(base + c * 1024 + rrx * 16 + h * 8) = o;
  }
}

static __device__ __forceinline__ void sc_compute(
    const unsigned short* __restrict__ buf, int e0,
    const short8 (&af)[4][7], const float* __restrict__ bias,
    int quad, int lr, float& sp, float& ss) {
  const char* base = (const char*)buf;
#pragma unroll
  for (int ni = 0; ni < 4; ni++) {
    int e = e0 + ni * 16 + lr;
    float bv = bias[e < NE ? e : 0];
    float b1v = (e < NE) ? bv : 0.f;
    floatx4 acc[4];
#pragma unroll
    for (int mi = 0; mi < 4; mi++) acc[mi] = (floatx4){0.f, 0.f, 0.f, 0.f};
#pragma unroll
    for (int kc = 0; kc < 7; kc++) {
      int c = kc * 4 + quad;
      int rrx = (ni * 16 + lr) ^ (c & 7);
      short8 bsv = *(const short8*)(base + c * 1024 + rrx * 16);
#pragma unroll
      for (int mi = 0; mi < 4; mi++)
        acc[mi] = __builtin_amdgcn_mfma_f32_16x16x32_bf16(af[mi][kc], bsv, acc[mi], 0, 0, 0);
    }
    // softplus in log2 domain: softplus(s) = ln2*(max(m1,0)+log2(1+2^-|m1|))
#pragma unroll
    for (int mi = 0; mi < 4; mi++) {
#pragma unroll
      for (int rg2 = 0; rg2 < 4; rg2++) {
        float s1 = acc[mi][rg2] + b1v;
        ss += s1;
        float m1 = s1 * 1.4426950408889634f;
        float e2 = __builtin_amdgcn_exp2f(-__builtin_fabsf(m1));
        float lg = __builtin_amdgcn_logf(1.f + e2);   // log2(1+e2)
        sp += fmaxf(m1, 0.f) + lg;
      }
    }
  }
}

__global__ __launch_bounds__(512)
__attribute__((amdgpu_waves_per_eu(2, 2)))
void k_scores5(
    const float* __restrict__ ent,            // [NE][200] f32 (converted in-kernel)
    const unsigned short* __restrict__ xfb,   // [512][KP] bf16 bits
    const float* __restrict__ bias, double* dacc) {
  __shared__ unsigned short Bs[2][14336];     // 2 x 28 KB
  __shared__ float sbuf[8];
  int t = threadIdx.x;
  int wv = t >> 6, lane = t & 63;
  int quad = lane >> 4, lr = lane & 15;

  short8 af[4][7];
#pragma unroll
  for (int mi = 0; mi < 4; mi++) {
    const unsigned short* ap = xfb + (size_t)(wv * 64 + mi * 16 + lr) * KP + quad * 8;
#pragma unroll
    for (int kc = 0; kc < 7; kc++) af[mi][kc] = *(const short8*)(ap + kc * 32);
  }

  int tile0 = blockIdx.x * 3;
  int e0_0 = tile0 * 64, e0_1 = e0_0 + 64, e0_2 = e0_0 + 128;
  float sp = 0.f, ss = 0.f;
  float4 rg[7];

  // prologue: stage tile0, issue tile1 loads
  sc_stage_issue(ent, e0_0, t, rg);
  sc_stage_commit(Bs[0], t, rg);      // compiler waits vmcnt on rg use
  sc_stage_issue(ent, e0_1, t, rg);
  __syncthreads();

  // t=0: compute buf0; commit tile1 -> buf1; issue tile2
  sc_compute(Bs[0], e0_0, af, bias, quad, lr, sp, ss);
  sc_stage_commit(Bs[1], t, rg);
  sc_stage_issue(ent, e0_2, t, rg);
  __syncthreads();

  // t=1: compute buf1; commit tile2 -> buf0
  sc_compute(Bs[1], e0_1, af, bias, quad, lr, sp, ss);
  sc_stage_commit(Bs[0], t, rg);
  __syncthreads();

  // t=2: compute buf0
  sc_compute(Bs[0], e0_2, af, bias, quad, lr, sp, ss);

  sp *= 0.6931471805599453f;  // ln2
  float tsp = blk_reduce(sp, sbuf);
  float tss = blk_reduce(ss, sbuf);
  if (t == 0) {
    atomicAdd(&dacc[68], (double)tsp);
    atomicAdd(&dacc[69], (double)tss);
  }
}

// K8: final scalar (64 threads; also does conv_w L2 reduce).
// Subtract pad softplus constant: 512 rows x 32 pad entities x ln2.
__global__ void k_final(const float* __restrict__ convw, const double* dacc, float* out) {
  int t = threadIdx.x;
  float sq = 0.f;
  for (int i = t; i < 288; i += 64) { float w = convw[i]; sq += w * w; }
  for (int o = 32; o > 0; o >>= 1) sq += __shfl_down(sq, o, 64);
  if (t == 0) {
    double SP = dacc[68] - 16384.0 * 0.6931471805599453;
    double S2 = dacc[69], S3 = dacc[70];
    double xy = S2 / (double)NE + 0.9 * S3;
    double kg = (SP - xy) / ((double)NB_B * (double)NE);
    double l2 = dacc[1] / 204800.0 + (double)sq / 576.0 + dacc[67] / 400.0;
    out[0] = (float)(kg + 1e-5 * l2);
  }
}

extern "C" void kernel_launch(void* const* d_in, const int* in_sizes, int n_in,
                              void* d_out, int out_size, void* d_ws, size_t ws_size,
                              hipStream_t stream) {
  const float* ent   = (const float*)d_in[0];
  const float* rel   = (const float*)d_in[1];
  const float* convw = (const float*)d_in[2];
  const float* convb = (const float*)d_in[3];
  const float* fcw   = (const float*)d_in[4];
  const float* fcb   = (const float*)d_in[5];
  const float* bias  = (const float*)d_in[6];
  const float* g0    = (const float*)d_in[7];
  const float* b0    = (const float*)d_in[8];
  const float* g1    = (const float*)d_in[9];
  const float* b1    = (const float*)d_in[10];
  const float* g2    = (const float*)d_in[11];
  const float* b2    = (const float*)d_in[12];
  const int*   h     = (const int*)d_in[13];
  const int*   r     = (const int*)d_in[14];
  const int*   pos   = (const int*)d_in[15];

  char* ws = (char*)d_ws;
  double* dacc = (double*)(ws + 0);                        // 8 KB
  float* a2  = (float*)(ws + 16384 + 256);                 // 200
  float* b2c = (float*)(ws + 16384 + 1056);                // 200
  float* x0  = (float*)(ws + 32768);                       // 512*400 f32      (819200 B)
  float* Cfc = (float*)(ws + 851968);                      // 512*200 f32      (409600 B)
  float* xf  = (float*)(ws + 1261568);                     // 512*200 f32      (409600 B)
  unsigned short* yb   = (unsigned short*)(ws + 1671168);  // 512*10368 bf16   (10616832 B)
  unsigned short* fcwb = (unsigned short*)(ws + 12288000); // 200*10368 bf16   (4147200 B)
  unsigned short* xfb  = (unsigned short*)(ws + 16435200); // 512*224 bf16     (229376 B)
  float* Cp = (float*)(ws + 16664576);                     // 12*512*200 f32   (4915200 B)

  hipMemsetAsync(dacc, 0, 8192, stream);

  k_cvt<<<FCW_BLKS + 512, 256, 0, stream>>>(fcw, fcwb, ent, rel, h, r, x0, dacc);
  k_conv<<<512, 256, 0, stream>>>(x0, convw, convb, g0, b0, yb, dacc);
  k_prep<<<2592, 256, 0, stream>>>(yb, g1, b1, dacc);
  k_fc3<<<384, 64, 0, stream>>>(yb, fcwb, Cp);
  k_fcred<<<100, 256, 0, stream>>>(Cp, Cfc);
  k_bn2stats<<<200, 64, 0, stream>>>(Cfc, fcb, g2, b2, a2, b2c);
  k_xfinal<<<512, 256, 0, stream>>>(Cfc, fcb, a2, b2c, ent, bias, pos, xf, xfb, dacc);
  k_scores5<<<521, 512, 0, stream>>>(ent, xfb, bias, dacc);
  k_final<<<1, 64, 0, stream>>>(convw, dacc, (float*)d_out);
}

// Round 11
// 295.234 us; speedup vs baseline: 1.3024x; 1.3024x over previous
//
#include <hip/hip_runtime.h>
#include <math.h>

#define NB_B 512
#define NE 100000
#define DD 200
#define CC 32
#define FCIN 10368   // 32*18*18
#define HW 324       // 18*18
#define BNEPS 1e-5f
#define KP 224       // scores K padded to multiple of 32 for MFMA

#define FCW_BLKS 1013
#define GATH_OFF FCW_BLKS   // gather blocks start here

typedef __attribute__((ext_vector_type(8))) short short8;   // 8 bf16 = 4 VGPRs
typedef __attribute__((ext_vector_type(4))) float floatx4;  // MFMA acc

// dacc (double) slots:
// 0: bn0 sum, 1: bn0 sumsq (also l2 for h_e+r_e)
// 2..33: bn1 per-channel sum, 34..65: bn1 per-channel sumsq
// 67: fc_w sumsq, 68: softplus sum (incl. pad constant), 69: scores sum, 70: pos-scores sum

static __device__ __forceinline__ float blk_reduce(float v, volatile float* sbuf) {
  for (int o = 32; o > 0; o >>= 1) v += __shfl_down(v, o, 64);
  int lane = threadIdx.x & 63, wid = threadIdx.x >> 6;
  if (lane == 0) sbuf[wid] = v;
  __syncthreads();
  float r = 0.f;
  int nw = (blockDim.x + 63) >> 6;
  if ((int)threadIdx.x < nw) r = sbuf[threadIdx.x];
  if (threadIdx.x < 64) {
    for (int o = 32; o > 0; o >>= 1) r += __shfl_down(r, o, 64);
  }
  __syncthreads();
  return r;  // valid on thread 0
}

static __device__ __forceinline__ unsigned short f32_to_bf16(float f) {
  unsigned int u = __float_as_uint(f);
  u += 0x7fffu + ((u >> 16) & 1u);  // round-to-nearest-even
  return (unsigned short)(u >> 16);
}
static __device__ __forceinline__ float bf16_to_f32(unsigned short b) {
  return __uint_as_float(((unsigned int)b) << 16);
}

// K1: fused prep. Blocks [0,FCW_BLKS): fc_w -> bf16 + sumsq.
// Blocks [GATH_OFF, +512): gather h/r -> x0, bn0 stats.
// (entity f32->bf16 conversion fused into k_scores6 staging)
__global__ __launch_bounds__(256) void k_cvt(const float* __restrict__ fcw,
                                             unsigned short* __restrict__ fcwb,
                                             const float* __restrict__ ent,
                                             const float* __restrict__ rel,
                                             const int* __restrict__ h,
                                             const int* __restrict__ r,
                                             float* __restrict__ x0,
                                             double* dacc) {
  if (blockIdx.x < FCW_BLKS) {
    int g = blockIdx.x * 256 + threadIdx.x;   // x8 elems; 2,073,600 total
    float sq = 0.f;
    if (g < 259200) {
      const float4* s = (const float4*)(fcw + (long)g * 8);
      float4 u = s[0], v = s[1];
      sq = u.x*u.x + u.y*u.y + u.z*u.z + u.w*u.w
         + v.x*v.x + v.y*v.y + v.z*v.z + v.w*v.w;
      ushort4 o0, o1;
      o0.x = f32_to_bf16(u.x); o0.y = f32_to_bf16(u.y);
      o0.z = f32_to_bf16(u.z); o0.w = f32_to_bf16(u.w);
      o1.x = f32_to_bf16(v.x); o1.y = f32_to_bf16(v.y);
      o1.z = f32_to_bf16(v.z); o1.w = f32_to_bf16(v.w);
      ushort4* d = (ushort4*)(fcwb + (long)g * 8);
      d[0] = o0; d[1] = o1;
    }
    __shared__ float sbuf[8];
    float tq = blk_reduce(sq, sbuf);
    if (threadIdx.x == 0) atomicAdd(&dacc[67], (double)tq);
  } else {
    int b = blockIdx.x - GATH_OFF;
    int hi = h[b], ri = r[b];
    float s = 0.f, sq = 0.f;
    for (int i = threadIdx.x; i < 400; i += 256) {
      float v = (i < 200) ? ent[(long)hi * DD + i] : rel[(long)ri * DD + (i - 200)];
      x0[b * 400 + i] = v;
      s += v; sq += v * v;
    }
    __shared__ float sbuf[8];
    float ts = blk_reduce(s, sbuf);
    float tq = blk_reduce(sq, sbuf);
    if (threadIdx.x == 0) {
      atomicAdd(&dacc[0], (double)ts);
      atomicAdd(&dacc[1], (double)tq);
    }
  }
}

// K2: bn0 + conv3x3 + conv_b -> yb bf16 [512 x 10368] (pre-bn1); bn1 stats (f32)
__global__ __launch_bounds__(256) void k_conv(const float* __restrict__ x0,
                       const float* __restrict__ convw, const float* __restrict__ convb,
                       const float* __restrict__ g0, const float* __restrict__ b0,
                       unsigned short* __restrict__ yb, double* dacc) {
  __shared__ float xs[400], wsm[288], cbs[32], ssum[32], ssq[32];
  __shared__ float a0s, s0s;
  int b = blockIdx.x, t = threadIdx.x;
  for (int i = t; i < 400; i += 256) xs[i] = x0[b * 400 + i];
  for (int i = t; i < 288; i += 256) wsm[i] = convw[i];
  if (t < 32) cbs[t] = convb[t];
  if (t == 0) {
    double m = dacc[0] / 204800.0;
    double v = dacc[1] / 204800.0 - m * m;
    float a = g0[0] * rsqrtf((float)v + BNEPS);
    a0s = a; s0s = b0[0] - (float)m * a;
  }
  __syncthreads();
  float a0 = a0s, s0 = s0s;
  for (int i = t; i < 400; i += 256) xs[i] = a0 * xs[i] + s0;
  __syncthreads();
  int c = t >> 3, sub = t & 7;
  const float* w = &wsm[c * 9];
  float cb = cbs[c];
  float s = 0.f, sq = 0.f;
  for (int e = sub; e < HW; e += 8) {
    int oh = e / 18, ow = e - oh * 18;
    const float* xp = &xs[oh * 20 + ow];
    float acc = cb
       + xp[0] * w[0] + xp[1] * w[1] + xp[2] * w[2]
       + xp[20] * w[3] + xp[21] * w[4] + xp[22] * w[5]
       + xp[40] * w[6] + xp[41] * w[7] + xp[42] * w[8];
    yb[(long)b * FCIN + c * HW + e] = f32_to_bf16(acc);
    s += acc; sq += acc * acc;
  }
  s += __shfl_xor(s, 1, 64); sq += __shfl_xor(sq, 1, 64);
  s += __shfl_xor(s, 2, 64); sq += __shfl_xor(sq, 2, 64);
  s += __shfl_xor(s, 4, 64); sq += __shfl_xor(sq, 4, 64);
  if (sub == 0) { ssum[c] = s; ssq[c] = sq; }
  __syncthreads();
  if (t < 32) {
    atomicAdd(&dacc[2 + t], (double)ssum[t]);
    atomicAdd(&dacc[34 + t], (double)ssq[t]);
  }
}

// K3: in-place bn1 + relu on yb (bf16); a1/sh1 computed per-block from dacc
__global__ __launch_bounds__(256) void k_prep(unsigned short* __restrict__ yb,
                                              const float* __restrict__ g1,
                                              const float* __restrict__ b1,
                                              const double* __restrict__ dacc) {
  __shared__ float a1s[32], sh1s[32];
  int t = threadIdx.x;
  if (t < 32) {
    double cnt = 512.0 * 324.0;
    double m = dacc[2 + t] / cnt, v = dacc[34 + t] / cnt - m * m;
    float a = g1[t] * rsqrtf((float)v + BNEPS);
    a1s[t] = a; sh1s[t] = b1[t] - (float)m * a;
  }
  __syncthreads();
  int g = blockIdx.x * 256 + t;          // 0..663551 (x8 elems)
  int row = g / 1296;
  int c8 = (g - row * 1296) * 8;
  unsigned short* p = yb + (long)row * FCIN + c8;
  ushort4 v0 = ((ushort4*)p)[0], v1 = ((ushort4*)p)[1];
  unsigned short e[8] = {v0.x, v0.y, v0.z, v0.w, v1.x, v1.y, v1.z, v1.w};
#pragma unroll
  for (int j = 0; j < 8; j++) {
    int c = (c8 + j) / HW;
    float f = a1s[c] * bf16_to_f32(e[j]) + sh1s[c];
    e[j] = f32_to_bf16(fmaxf(f, 0.f));
  }
  v0.x = e[0]; v0.y = e[1]; v0.z = e[2]; v0.w = e[3];
  v1.x = e[4]; v1.y = e[5]; v1.z = e[6]; v1.w = e[7];
  ((ushort4*)p)[0] = v0; ((ushort4*)p)[1] = v1;
}

// K4: FC GEMM via bf16 MFMA. 384 single-wave blocks = 12 kslices x (8 mt x 4 nt).
__global__ __launch_bounds__(64) void k_fc3(const unsigned short* __restrict__ yb,
                                            const unsigned short* __restrict__ fcwb,
                                            float* __restrict__ Cp) {
  int wid = blockIdx.x;             // 384 = 12 ks * 32 tiles
  int ks = wid >> 5, rem = wid & 31;
  int mt = rem >> 2, nt = rem & 3;
  int m0 = mt * 64, n0 = nt * 64;
  int lane = threadIdx.x;
  int quad = lane >> 4, lr = lane & 15;
  long kbeg = (long)ks * 864;       // 27 chunks of 32

  const unsigned short* arow[4];
  const unsigned short* brow[4];
#pragma unroll
  for (int mi = 0; mi < 4; mi++)
    arow[mi] = yb + (long)(m0 + mi * 16 + lr) * FCIN + kbeg + quad * 8;
#pragma unroll
  for (int ni = 0; ni < 4; ni++) {
    int d = n0 + ni * 16 + lr;
    if (d > DD - 1) d = DD - 1;
    brow[ni] = fcwb + (long)d * FCIN + kbeg + quad * 8;
  }

  floatx4 acc[4][4];
#pragma unroll
  for (int i = 0; i < 4; i++)
#pragma unroll
    for (int j = 0; j < 4; j++) acc[i][j] = (floatx4){0.f, 0.f, 0.f, 0.f};

  short8 sA[3][4], sB[3][4];
#pragma unroll
  for (int c = 0; c < 3; c++) {
#pragma unroll
    for (int mi = 0; mi < 4; mi++) sA[c][mi] = *(const short8*)(arow[mi] + c * 32);
#pragma unroll
    for (int ni = 0; ni < 4; ni++) sB[c][ni] = *(const short8*)(brow[ni] + c * 32);
  }
  for (int c3 = 0; c3 < 9; c3++) {
    int cc = c3 * 3;
#pragma unroll
    for (int j = 0; j < 3; j++) {
#pragma unroll
      for (int ni = 0; ni < 4; ni++)
#pragma unroll
        for (int mi = 0; mi < 4; mi++)
          acc[mi][ni] = __builtin_amdgcn_mfma_f32_16x16x32_bf16(sA[j][mi], sB[j][ni], acc[mi][ni], 0, 0, 0);
      int nxt = cc + j + 3;
      if (nxt < 27) {
#pragma unroll
        for (int mi = 0; mi < 4; mi++) sA[j][mi] = *(const short8*)(arow[mi] + nxt * 32);
#pragma unroll
        for (int ni = 0; ni < 4; ni++) sB[j][ni] = *(const short8*)(brow[ni] + nxt * 32);
      }
    }
  }

  float* out = Cp + (long)ks * (NB_B * DD);
#pragma unroll
  for (int ni = 0; ni < 4; ni++) {
    int d = n0 + ni * 16 + lr;
    if (d < DD) {
#pragma unroll
      for (int mi = 0; mi < 4; mi++) {
        int mbase = m0 + mi * 16 + quad * 4;
#pragma unroll
        for (int rg = 0; rg < 4; rg++)
          out[(mbase + rg) * DD + d] = acc[mi][ni][rg];
      }
    }
  }
}

// K4b: reduce 12 partials -> Cfc. 102400 floats = 25600 float4.
__global__ __launch_bounds__(256) void k_fcred(const float* __restrict__ Cp,
                                               float* __restrict__ Cfc) {
  int g = blockIdx.x * 256 + threadIdx.x;   // 0..25599
  float4 s = ((const float4*)Cp)[g];
#pragma unroll
  for (int p = 1; p < 12; p++) {
    float4 v = ((const float4*)(Cp + (long)p * (NB_B * DD)))[g];
    s.x += v.x; s.y += v.y; s.z += v.z; s.w += v.w;
  }
  ((float4*)Cfc)[g] = s;
}

// K5: bn2 stats per feature -> a2/b2c
__global__ void k_bn2stats(const float* __restrict__ Cfc, const float* __restrict__ fcb,
                           const float* __restrict__ g2, const float* __restrict__ b2,
                           float* __restrict__ a2, float* __restrict__ b2c) {
  int d = blockIdx.x, lane = threadIdx.x;  // 64 threads
  float s = 0.f, sq = 0.f;
  for (int b = lane; b < NB_B; b += 64) {
    float v = Cfc[b * DD + d] + fcb[d];
    s += v; sq += v * v;
  }
  for (int o = 32; o > 0; o >>= 1) { s += __shfl_down(s, o, 64); sq += __shfl_down(sq, o, 64); }
  if (lane == 0) {
    float m = s / 512.f, v = sq / 512.f - m * m;
    float a = g2[d] * rsqrtf(v + BNEPS);
    a2[d] = a; b2c[d] = b2[d] - m * a;
  }
}

// K6: x_final row: leaky_relu(bn2(fc)) -> xf f32 + xfb bf16(padded); fused pos-score
__global__ __launch_bounds__(256) void k_xfinal(const float* __restrict__ Cfc,
                         const float* __restrict__ fcb,
                         const float* __restrict__ a2, const float* __restrict__ b2c,
                         const float* __restrict__ ent, const float* __restrict__ bias,
                         const int* __restrict__ pos,
                         float* __restrict__ xf, unsigned short* __restrict__ xfb,
                         double* dacc) {
  __shared__ float xs[224];
  __shared__ float sbuf[8];
  int b = blockIdx.x, t = threadIdx.x;
  if (t < KP) {
    float xv = 0.f;
    if (t < DD) {
      float v = Cfc[b * DD + t] + fcb[t];
      xv = a2[t] * v + b2c[t];
      xv = xv >= 0.f ? xv : 0.01f * xv;
      xf[b * DD + t] = xv;
    }
    xfb[b * KP + t] = f32_to_bf16(xv);
    xs[t] = xv;
  }
  __syncthreads();
  int e = pos[b];
  float s = (t < DD) ? xs[t] * ent[(long)e * DD + t] : 0.f;
  float ts = blk_reduce(s, sbuf);
  if (t == 0) atomicAdd(&dacc[70], (double)(ts + bias[e]));
}

// ---------------------------------------------------------------------------
// K7: scores GEMM + fused softplus, LDS-staged entity tiles with fused
// f32->bf16 conversion.
//
// Round-7 post-mortem: both __launch_bounds__(512,2) and
// amdgpu_waves_per_eu(2,2) were ignored by the allocator (VGPR_Count=128,
// 140 MB scratch spill both times). Fix: make the kernel FIT in 128 VGPRs.
// The A-fragment file af[4][7] (112 VGPRs) was the blowout -> halve it:
// each wave owns 32 batch rows (af[2][7] = 56 VGPRs); a block covers
// 256 rows x 192 entities; grid = 1042 (b&1 = row half, b>>1 = tile triple).
// Live set: af 56 + rg 28 + acc[2] 8 + bsv 4 + misc ~15 = ~111 < 128.
// Adjacent blocks (2k, 2k+1) stage the same entity tiles; the 80 MB entity
// region fits L3, so the duplicate stage is an L3 hit, not extra HBM.
// ---------------------------------------------------------------------------
static __device__ __forceinline__ void sc_stage_issue(
    const float* __restrict__ ent, int e0, int t, float4 (&rg)[7]) {
#pragma unroll
  for (int i = 0; i < 7; i++) {
    int u = t + i * 512;           // 0..3583
    int rr = u / 56, j = u - rr * 56;
    int e = e0 + rr;
    float4 v; v.x = 0.f; v.y = 0.f; v.z = 0.f; v.w = 0.f;
    if (j < 50 && e < NE) v = *(const float4*)(ent + (long)e * DD + j * 4);
    rg[i] = v;
  }
}

static __device__ __forceinline__ void sc_stage_commit(
    unsigned short* __restrict__ buf, int t, const float4 (&rg)[7]) {
  char* base = (char*)buf;
#pragma unroll
  for (int i = 0; i < 7; i++) {
    int u = t + i * 512;
    int rr = u / 56, j = u - rr * 56;
    int c = j >> 1, h = j & 1;
    int rrx = rr ^ (c & 7);
    ushort4 o;
    o.x = f32_to_bf16(rg[i].x); o.y = f32_to_bf16(rg[i].y);
    o.z = f32_to_bf16(rg[i].z); o.w = f32_to_bf16(rg[i].w);
    *(ushort4*)(base + c * 1024 + rrx * 16 + h * 8) = o;
  }
}

static __device__ __forceinline__ void sc_compute(
    const unsigned short* __restrict__ buf, int e0,
    const short8 (&af)[2][7], const float* __restrict__ bias,
    int quad, int lr, float& sp, float& ss) {
  const char* base = (const char*)buf;
#pragma unroll
  for (int ni = 0; ni < 4; ni++) {
    int e = e0 + ni * 16 + lr;
    float bv = bias[e < NE ? e : 0];
    float b1v = (e < NE) ? bv : 0.f;
    floatx4 acc0 = (floatx4){0.f, 0.f, 0.f, 0.f};
    floatx4 acc1 = (floatx4){0.f, 0.f, 0.f, 0.f};
#pragma unroll
    for (int kc = 0; kc < 7; kc++) {
      int c = kc * 4 + quad;
      int rrx = (ni * 16 + lr) ^ (c & 7);
      short8 bsv = *(const short8*)(base + c * 1024 + rrx * 16);
      acc0 = __builtin_amdgcn_mfma_f32_16x16x32_bf16(af[0][kc], bsv, acc0, 0, 0, 0);
      acc1 = __builtin_amdgcn_mfma_f32_16x16x32_bf16(af[1][kc], bsv, acc1, 0, 0, 0);
    }
    // softplus in log2 domain: softplus(s) = ln2*(max(m1,0)+log2(1+2^-|m1|))
#pragma unroll
    for (int rg2 = 0; rg2 < 4; rg2++) {
      float s1 = acc0[rg2] + b1v;
      ss += s1;
      float m1 = s1 * 1.4426950408889634f;
      float e2 = __builtin_amdgcn_exp2f(-__builtin_fabsf(m1));
      sp += fmaxf(m1, 0.f) + __builtin_amdgcn_logf(1.f + e2);
    }
#pragma unroll
    for (int rg2 = 0; rg2 < 4; rg2++) {
      float s1 = acc1[rg2] + b1v;
      ss += s1;
      float m1 = s1 * 1.4426950408889634f;
      float e2 = __builtin_amdgcn_exp2f(-__builtin_fabsf(m1));
      sp += fmaxf(m1, 0.f) + __builtin_amdgcn_logf(1.f + e2);
    }
  }
}

__global__ __launch_bounds__(512) void k_scores6(
    const float* __restrict__ ent,            // [NE][200] f32 (converted in-kernel)
    const unsigned short* __restrict__ xfb,   // [512][KP] bf16 bits
    const float* __restrict__ bias, double* dacc) {
  __shared__ unsigned short Bs[2][14336];     // 2 x 28 KB
  __shared__ float sbuf[8];
  int t = threadIdx.x;
  int wv = t >> 6, lane = t & 63;
  int quad = lane >> 4, lr = lane & 15;
  int b = blockIdx.x;
  int rh = b & 1;                 // row half: rows [rh*256, rh*256+256)
  int tile0 = (b >> 1) * 3;       // 521 tile-triples

  short8 af[2][7];
#pragma unroll
  for (int mi = 0; mi < 2; mi++) {
    const unsigned short* ap =
        xfb + (size_t)(rh * 256 + wv * 32 + mi * 16 + lr) * KP + quad * 8;
#pragma unroll
    for (int kc = 0; kc < 7; kc++) af[mi][kc] = *(const short8*)(ap + kc * 32);
  }

  int e0_0 = tile0 * 64, e0_1 = e0_0 + 64, e0_2 = e0_0 + 128;
  float sp = 0.f, ss = 0.f;
  float4 rg[7];

  // prologue: stage tile0, issue tile1 loads
  sc_stage_issue(ent, e0_0, t, rg);
  sc_stage_commit(Bs[0], t, rg);      // compiler waits vmcnt on rg use
  sc_stage_issue(ent, e0_1, t, rg);
  __syncthreads();

  // t=0: compute buf0; commit tile1 -> buf1; issue tile2
  sc_compute(Bs[0], e0_0, af, bias, quad, lr, sp, ss);
  sc_stage_commit(Bs[1], t, rg);
  sc_stage_issue(ent, e0_2, t, rg);
  __syncthreads();

  // t=1: compute buf1; commit tile2 -> buf0
  sc_compute(Bs[1], e0_1, af, bias, quad, lr, sp, ss);
  sc_stage_commit(Bs[0], t, rg);
  __syncthreads();

  // t=2: compute buf0
  sc_compute(Bs[0], e0_2, af, bias, quad, lr, sp, ss);

  sp *= 0.6931471805599453f;  // ln2
  float tsp = blk_reduce(sp, sbuf);
  float tss = blk_reduce(ss, sbuf);
  if (t == 0) {
    atomicAdd(&dacc[68], (double)tsp);
    atomicAdd(&dacc[69], (double)tss);
  }
}

// K8: final scalar (64 threads; also does conv_w L2 reduce).
// Subtract pad softplus constant: 512 rows x 32 pad entities x ln2
// (each pad entity meets each of the 512 rows exactly once across the
// two row-halves).
__global__ void k_final(const float* __restrict__ convw, const double* dacc, float* out) {
  int t = threadIdx.x;
  float sq = 0.f;
  for (int i = t; i < 288; i += 64) { float w = convw[i]; sq += w * w; }
  for (int o = 32; o > 0; o >>= 1) sq += __shfl_down(sq, o, 64);
  if (t == 0) {
    double SP = dacc[68] - 16384.0 * 0.6931471805599453;
    double S2 = dacc[69], S3 = dacc[70];
    double xy = S2 / (double)NE + 0.9 * S3;
    double kg = (SP - xy) / ((double)NB_B * (double)NE);
    double l2 = dacc[1] / 204800.0 + (double)sq / 576.0 + dacc[67] / 400.0;
    out[0] = (float)(kg + 1e-5 * l2);
  }
}

extern "C" void kernel_launch(void* const* d_in, const int* in_sizes, int n_in,
                              void* d_out, int out_size, void* d_ws, size_t ws_size,
                              hipStream_t stream) {
  const float* ent   = (const float*)d_in[0];
  const float* rel   = (const float*)d_in[1];
  const float* convw = (const float*)d_in[2];
  const float* convb = (const float*)d_in[3];
  const float* fcw   = (const float*)d_in[4];
  const float* fcb   = (const float*)d_in[5];
  const float* bias  = (const float*)d_in[6];
  const float* g0    = (const float*)d_in[7];
  const float* b0    = (const float*)d_in[8];
  const float* g1    = (const float*)d_in[9];
  const float* b1    = (const float*)d_in[10];
  const float* g2    = (const float*)d_in[11];
  const float* b2    = (const float*)d_in[12];
  const int*   h     = (const int*)d_in[13];
  const int*   r     = (const int*)d_in[14];
  const int*   pos   = (const int*)d_in[15];

  char* ws = (char*)d_ws;
  double* dacc = (double*)(ws + 0);                        // 8 KB
  float* a2  = (float*)(ws + 16384 + 256);                 // 200
  float* b2c = (float*)(ws + 16384 + 1056);                // 200
  float* x0  = (float*)(ws + 32768);                       // 512*400 f32      (819200 B)
  float* Cfc = (float*)(ws + 851968);                      // 512*200 f32      (409600 B)
  float* xf  = (float*)(ws + 1261568);                     // 512*200 f32      (409600 B)
  unsigned short* yb   = (unsigned short*)(ws + 1671168);  // 512*10368 bf16   (10616832 B)
  unsigned short* fcwb = (unsigned short*)(ws + 12288000); // 200*10368 bf16   (4147200 B)
  unsigned short* xfb  = (unsigned short*)(ws + 16435200); // 512*224 bf16     (229376 B)
  float* Cp = (float*)(ws + 16664576);                     // 12*512*200 f32   (4915200 B)

  hipMemsetAsync(dacc, 0, 8192, stream);

  k_cvt<<<FCW_BLKS + 512, 256, 0, stream>>>(fcw, fcwb, ent, rel, h, r, x0, dacc);
  k_conv<<<512, 256, 0, stream>>>(x0, convw, convb, g0, b0, yb, dacc);
  k_prep<<<2592, 256, 0, stream>>>(yb, g1, b1, dacc);
  k_fc3<<<384, 64, 0, stream>>>(yb, fcwb, Cp);
  k_fcred<<<100, 256, 0, stream>>>(Cp, Cfc);
  k_bn2stats<<<200, 64, 0, stream>>>(Cfc, fcb, g2, b2, a2, b2c);
  k_xfinal<<<512, 256, 0, stream>>>(Cfc, fcb, a2, b2c, ent, bias, pos, xf, xfb, dacc);
  k_scores6<<<1042, 512, 0, stream>>>(ent, xfb, bias, dacc);
  k_final<<<1, 64, 0, stream>>>(convw, dacc, (float*)d_out);
}